// Round 13
// baseline (202.105 us; speedup 1.0000x reference)
//
#include <hip/hip_runtime.h>
#include <hip/hip_bf16.h>
#include <stdint.h>

typedef int i32x4 __attribute__((ext_vector_type(4)));
typedef float f32x4 __attribute__((ext_vector_type(4)));

#define K_DIM 2048
#define M_DIM 8192   // B*S = 4*2048 tokens
#define N_DIM 8192   // D_OUT
#define QBF   127.0f
#define EPSF  1e-5f
#define NT    32     // K_DIM / 64 sub-tiles (BK=64)

__device__ __forceinline__ void load_lds16(const void* gsrc, void* ldst) {
    __builtin_amdgcn_global_load_lds(
        (__attribute__((address_space(1))) void*)gsrc,
        (__attribute__((address_space(3))) void*)ldst,
        16, 0, 0);
}

// ---------- Kernel 1: deterministic partial |W| sums ----------
__global__ __launch_bounds__(256) void k_abs_partial(const float* __restrict__ w,
                                                     float* __restrict__ partial) {
    __shared__ float red[256];
    int t = threadIdx.x, b = blockIdx.x;
    const float4* w4 = (const float4*)w;
    size_t base = (size_t)b * 2048;
    float s = 0.f;
#pragma unroll
    for (int j = 0; j < 8; ++j) {
        float4 v = w4[base + j * 256 + t];
        s += fabsf(v.x) + fabsf(v.y) + fabsf(v.z) + fabsf(v.w);
    }
    red[t] = s; __syncthreads();
    for (int off = 128; off > 0; off >>= 1) {
        if (t < off) red[t] += red[t + off];
        __syncthreads();
    }
    if (t == 0) partial[b] = red[0];
}

// ---------- Kernel 2: gamma = sum(partial)/count ----------
__global__ __launch_bounds__(256) void k_gamma(const float* __restrict__ partial,
                                               float* __restrict__ gamma) {
    __shared__ float red[256];
    int t = threadIdx.x;
    float s = 0.f;
#pragma unroll
    for (int j = 0; j < 8; ++j) s += partial[t + j * 256];
    red[t] = s; __syncthreads();
    for (int off = 128; off > 0; off >>= 1) {
        if (t < off) red[t] += red[t + off];
        __syncthreads();
    }
    if (t == 0) gamma[0] = red[0] / 16777216.0f;
}

// ---------- Kernel 3: ternary-quantize W -> int8 ----------
__global__ __launch_bounds__(256) void k_quant_w(const float* __restrict__ w,
                                                 const float* __restrict__ gamma,
                                                 uint* __restrict__ wq) {
    float g = fmaxf(gamma[0], EPSF);
    int tid = blockIdx.x * 256 + threadIdx.x;    // 4,194,304 threads
    float4 v = ((const float4*)w)[tid];
    int a = (int)fminf(fmaxf(rintf(v.x / g), -1.f), 1.f);
    int b = (int)fminf(fmaxf(rintf(v.y / g), -1.f), 1.f);
    int c = (int)fminf(fmaxf(rintf(v.z / g), -1.f), 1.f);
    int d = (int)fminf(fmaxf(rintf(v.w / g), -1.f), 1.f);
    wq[tid] = (a & 255) | ((b & 255) << 8) | ((c & 255) << 16) | ((d & 255) << 24);
}

// ---------- Kernel 4: per-token absmax-quantize x -> int8, alpha ----------
__global__ __launch_bounds__(256) void k_quant_x(const float* __restrict__ x,
                                                 uint* __restrict__ xq,
                                                 float* __restrict__ alpha) {
    __shared__ float red[256];
    int t = threadIdx.x, row = blockIdx.x;
    const float4* x4 = (const float4*)x + (size_t)row * 512;
    float4 v0 = x4[t], v1 = x4[t + 256];
    float m = fmaxf(fmaxf(fabsf(v0.x), fabsf(v0.y)), fmaxf(fabsf(v0.z), fabsf(v0.w)));
    m = fmaxf(m, fmaxf(fmaxf(fabsf(v1.x), fabsf(v1.y)), fmaxf(fabsf(v1.z), fabsf(v1.w))));
    red[t] = m; __syncthreads();
    for (int off = 128; off > 0; off >>= 1) {
        if (t < off) red[t] = fmaxf(red[t], red[t + off]);
        __syncthreads();
    }
    float a = red[0];
    if (t == 0) alpha[row] = a;
    float den = fmaxf(a, EPSF);
    uint* q = xq + (size_t)row * 512;
    int q0 = (int)fminf(fmaxf(rintf(v0.x * QBF / den), -QBF), QBF);
    int q1 = (int)fminf(fmaxf(rintf(v0.y * QBF / den), -QBF), QBF);
    int q2 = (int)fminf(fmaxf(rintf(v0.z * QBF / den), -QBF), QBF);
    int q3 = (int)fminf(fmaxf(rintf(v0.w * QBF / den), -QBF), QBF);
    q[t] = (q0 & 255) | ((q1 & 255) << 8) | ((q2 & 255) << 16) | ((q3 & 255) << 24);
    q0 = (int)fminf(fmaxf(rintf(v1.x * QBF / den), -QBF), QBF);
    q1 = (int)fminf(fmaxf(rintf(v1.y * QBF / den), -QBF), QBF);
    q2 = (int)fminf(fmaxf(rintf(v1.z * QBF / den), -QBF), QBF);
    q3 = (int)fminf(fmaxf(rintf(v1.w * QBF / den), -QBF), QBF);
    q[t + 256] = (q0 & 255) | ((q1 & 255) << 8) | ((q2 & 255) << 16) | ((q3 & 255) << 24);
}

// ---------- Kernel 5: 256x256 i8 GEMM, m201-style fine phases ----------
// R4 geometry verbatim (512 thr = 8 waves 2x4, wave tile 128x64, BK=64 subtile
// = 32KB, 0-conflict swizzle phys_chunk = logical ^ ((row>>1)&3)), depth-3 ring
// (96KB, 1 block/CU), recut into the m201 fine-phase schedule:
//   per subtile kt, 2 phases of {JIT ds_reads | 2 stage issues | BAR |
//   lgkmcnt(0)+sched_barrier | setprio(1) 16 MFMA setprio(0) | BAR}.
// Two barriers per 16-MFMA cluster preserve the soft inter-wave stagger (one
// wave's read burst fills the MFMA gap of waves already past the barrier) —
// the mechanism behind m201's 62% MfmaUtil vs our coarse 1-barrier 37%.
// vm ledger (4 stage issues/wave/subtile for kt+2, split 2+2 across phases):
//   at phase-B wait of kt: outstanding = kt+1's 4 + kt+2's 4 = 8 -> vmcnt(4)
//   retires kt+1 exactly; closing BAR certifies kt+1 for the next subtile.
//   kt >= NT-2: vmcnt(0) (no further prefetch outstanding). Never 0 mid-loop.
// Slot reuse: stage(kt+2) -> slot of kt-1, whose readers drained (lgkm0)
// before kt-1's closing barrier. Safe.
__global__ __launch_bounds__(512, 2) void k_gemm(const uint8_t* __restrict__ xq,
                                                 const uint8_t* __restrict__ wq,
                                                 const float* __restrict__ alpha,
                                                 const float* __restrict__ gamma,
                                                 float* __restrict__ out) {
    __shared__ __align__(16) char smem[98304];   // 3 ring slots x 32KB

    int bid = blockIdx.x;
    int wg = (bid & 7) * 128 + (bid >> 3);       // XCD-bijective (1024 % 8 == 0)
    int tm = wg >> 5, tn = wg & 31;              // 32 x 32 tiles of 256x256

    int t = threadIdx.x;
    int w = t >> 6, l = t & 63;
    int wr = w >> 2, wc = w & 3;                 // 2x4 waves, wave tile 128x64

    // ---- staging: 32 regions of 1KB (16 rows) per subtile, 4 per wave (R4)
    const uint8_t* srcb[4];
    int dstq[4];
    {
        int rsub = l >> 2;                       // row within 16-row region
        int clog = (l & 3) ^ ((rsub >> 1) & 3);  // pre-swizzled source chunk
#pragma unroll
        for (int j = 0; j < 4; ++j) {
            int q = w * 4 + j;                   // 0..31 (0-15 A, 16-31 B)
            int isB = q >> 4;
            int r = (q & 15) * 16 + rsub;        // tile-local row 0..255
            int grow = (isB ? tn : tm) * 256 + r;
            srcb[j] = (isB ? wq : xq) + (size_t)grow * K_DIM + clog * 16;
            dstq[j] = q * 1024;                  // wave-uniform; hw adds l*16
        }
    }

    i32x4 acc[8][4];
#pragma unroll
    for (int m = 0; m < 8; ++m)
#pragma unroll
        for (int n = 0; n < 4; ++n) acc[m][n] = (i32x4){0, 0, 0, 0};

    int lrow = l & 15, kgrp = l >> 4;
    int cph = (kgrp ^ ((lrow >> 1) & 3)) * 16;   // swizzled read chunk
    int aoff[8], boff[4];
#pragma unroll
    for (int mf = 0; mf < 8; ++mf) aoff[mf] = (wr * 128 + mf * 16 + lrow) * 64 + cph;
#pragma unroll
    for (int nf = 0; nf < 4; ++nf) boff[nf] = 16384 + (wc * 64 + nf * 16 + lrow) * 64 + cph;

    // ---- prologue: stage sub-tiles 0,1; certify 0
#pragma unroll
    for (int p = 0; p < 2; ++p)
#pragma unroll
        for (int j = 0; j < 4; ++j)
            load_lds16(srcb[j] + (size_t)p * 64, smem + p * 32768 + dstq[j]);
    asm volatile("s_waitcnt vmcnt(4)" ::: "memory");   // stage(0) landed
    __builtin_amdgcn_s_barrier();                      // all waves' stage(0)

    int slot = 0;
    for (int kt = 0; kt < NT; ++kt) {
        char* sb = smem + slot * 32768;
        int ds = slot + 2; if (ds >= 3) ds -= 3;
        char* db = smem + ds * 32768;
        bool pf = (kt + 2 < NT);
        i32x4 a[8], b[4];

        // ================= Phase A: B0-3 + A0-3 -> 16 MFMA =================
#pragma unroll
        for (int nf = 0; nf < 4; ++nf) b[nf] = *(const i32x4*)(sb + boff[nf]);
#pragma unroll
        for (int mf = 0; mf < 4; ++mf) a[mf] = *(const i32x4*)(sb + aoff[mf]);
        if (pf) {
            load_lds16(srcb[0] + (size_t)(kt + 2) * 64, db + dstq[0]);
            load_lds16(srcb[1] + (size_t)(kt + 2) * 64, db + dstq[1]);
        }
        __builtin_amdgcn_s_barrier();
        asm volatile("s_waitcnt lgkmcnt(0)" ::: "memory");
        __builtin_amdgcn_sched_barrier(0);
        __builtin_amdgcn_s_setprio(1);
#pragma unroll
        for (int mf = 0; mf < 4; ++mf)
#pragma unroll
            for (int nf = 0; nf < 4; ++nf)
                acc[mf][nf] = __builtin_amdgcn_mfma_i32_16x16x64_i8(
                    a[mf], b[nf], acc[mf][nf], 0, 0, 0);
        __builtin_amdgcn_s_setprio(0);
        __builtin_amdgcn_s_barrier();

        // ================= Phase B: A4-7 -> 16 MFMA =================
#pragma unroll
        for (int mf = 4; mf < 8; ++mf) a[mf] = *(const i32x4*)(sb + aoff[mf]);
        if (pf) {
            load_lds16(srcb[2] + (size_t)(kt + 2) * 64, db + dstq[2]);
            load_lds16(srcb[3] + (size_t)(kt + 2) * 64, db + dstq[3]);
        }
        __builtin_amdgcn_s_barrier();
        asm volatile("s_waitcnt lgkmcnt(0)" ::: "memory");
        __builtin_amdgcn_sched_barrier(0);
        __builtin_amdgcn_s_setprio(1);
#pragma unroll
        for (int mf = 4; mf < 8; ++mf)
#pragma unroll
            for (int nf = 0; nf < 4; ++nf)
                acc[mf][nf] = __builtin_amdgcn_mfma_i32_16x16x64_i8(
                    a[mf], b[nf], acc[mf][nf], 0, 0, 0);
        __builtin_amdgcn_s_setprio(0);
        // tile-boundary counted wait: retire kt+1's stages, keep kt+2's in flight
        if (kt < NT - 2) asm volatile("s_waitcnt vmcnt(4)" ::: "memory");
        else             asm volatile("s_waitcnt vmcnt(0)" ::: "memory");
        __builtin_amdgcn_s_barrier();            // certifies kt+1 for next iter

        slot = (slot == 2) ? 0 : slot + 1;
    }

    // ---- epilogue: LDS-transpose -> full-128B-line nontemporal f32x4 stores ----
    // C/D 16x16: col = lane&15, row = (lane>>4)*4 + reg. Per-wave 2x4352B dbuf,
    // row stride 68 dwords (kgrp shifts banks by 16 -> 2-way, free).
    asm volatile("s_waitcnt lgkmcnt(0)" ::: "memory");
    __builtin_amdgcn_s_barrier();                // ring slots safe to reuse
    float gs = gamma[0] / QBF;
    int orow0 = tm * 256 + wr * 128;
    int ocol0 = tn * 256 + wc * 64;
    int kgrp4 = kgrp * 4;
    char* ebase = smem + w * 8704;               // 8 waves x 8704 = 69632 <= 98304
#pragma unroll
    for (int mf = 0; mf < 8; ++mf) {
        float* eb = (float*)(ebase + (mf & 1) * 4352);
        int rbase = orow0 + mf * 16;
#pragma unroll
        for (int reg = 0; reg < 4; ++reg) {
            float s = alpha[rbase + kgrp4 + reg] * gs;
            int rowo = (kgrp4 + reg) * 68;
#pragma unroll
            for (int nf = 0; nf < 4; ++nf)
                eb[rowo + nf * 16 + lrow] = (float)acc[mf][nf][reg] * s;
        }
        asm volatile("s_waitcnt lgkmcnt(0)" ::: "memory");
        __builtin_amdgcn_sched_barrier(0);
#pragma unroll
        for (int pass = 0; pass < 4; ++pass) {
            int r16 = (pass >> 1) * 8 + (l >> 3);
            int fc  = (pass & 1) * 8 + (l & 7);
            f32x4 v = *(const f32x4*)(eb + r16 * 68 + fc * 4);
            __builtin_nontemporal_store(
                v, (f32x4*)(out + (size_t)(rbase + r16) * N_DIM + ocol0 + fc * 4));
        }
        asm volatile("s_waitcnt lgkmcnt(0)" ::: "memory");
        __builtin_amdgcn_sched_barrier(0);
    }
}

extern "C" void kernel_launch(void* const* d_in, const int* in_sizes, int n_in,
                              void* d_out, int out_size, void* d_ws, size_t ws_size,
                              hipStream_t stream) {
    const float* x  = (const float*)d_in[0];   // [4,2048,2048]
    const float* wt = (const float*)d_in[1];   // [8192,2048]
    float* out = (float*)d_out;                // [4,2048,8192] fp32

    char* ws = (char*)d_ws;
    uint8_t* xq     = (uint8_t*)ws;                     // 16,777,216 B
    uint8_t* wq     = (uint8_t*)(ws + 16777216);        // 16,777,216 B
    float* alpha    = (float*)(ws + 33554432);          // 32,768 B
    float* partial  = (float*)(ws + 33587200);          // 8,192 B
    float* gamma    = (float*)(ws + 33595392);          // 4 B

    k_abs_partial<<<2048, 256, 0, stream>>>(wt, partial);
    k_gamma<<<1, 256, 0, stream>>>(partial, gamma);
    k_quant_w<<<16384, 256, 0, stream>>>(wt, gamma, (uint*)wq);
    k_quant_x<<<8192, 256, 0, stream>>>(x, (uint*)xq, alpha);
    k_gemm<<<1024, 512, 0, stream>>>(xq, wq, alpha, gamma, out);
}